// Round 7
// baseline (465.168 us; speedup 1.0000x reference)
//
#include <hip/hip_runtime.h>

typedef int v4i __attribute__((ext_vector_type(4)));

#define MM 8192
#define KK 4096
#define NN 4096
#define NG 8
#define TILE_BYTES 8192          // packed tile: 128 rows x 64 k-bytes, swizzled
#define NKT 64                   // K / 64
#define A_TILES_M 64             // M / 128
#define B_TILES_N 32             // N / 128
#define AP_BYTES ((size_t)A_TILES_M * NKT * TILE_BYTES)      // 32 MB
#define BP_BYTES ((size_t)NG * B_TILES_N * NKT * TILE_BYTES) // 128 MB

#define BM 256
#define BN 256

// XOR swizzle within a 128-row x 64-byte tile (16B-slot granular).
__device__ __forceinline__ int swz(int row, int c) {
    int line = row >> 1;
    int s = ((((row & 1) << 2) | (c >> 4)) ^ ((row >> 2) & 7));
    return line * 128 + s * 16 + (c & 15);
}

__device__ __forceinline__ unsigned pack4(v4i v) {
    return (v.x & 255) | ((v.y & 255) << 8) | ((v.z & 255) << 16) |
           ((unsigned)v.w << 24);
}

// ---- pack A: int32 [M][K] -> int8 blocked [mt][kt][swz(128x64)] ----
__global__ __launch_bounds__(256)
void pack_a(const int* __restrict__ A, unsigned char* __restrict__ Ap)
{
    const int b  = blockIdx.x;
    const int mt = b >> 6;
    const int kt = b & 63;
    const int t  = threadIdx.x;
    unsigned char* dst = Ap + (size_t)b * TILE_BYTES;

    #pragma unroll
    for (int i = 0; i < 2; ++i) {
        const int p    = t + i * 256;       // 16B output slot index
        const int line = p >> 3, sl = p & 7;
        const int h    = (line >> 1) & 7;
        const int y    = sl ^ h;            // inverse swizzle
        const int row  = 2 * line + (y >> 2);
        const int c16  = y & 3;
        const int* src = A + (size_t)(mt * 128 + row) * KK + kt * 64 + c16 * 16;
        v4i x0 = ((const v4i*)src)[0];
        v4i x1 = ((const v4i*)src)[1];
        v4i x2 = ((const v4i*)src)[2];
        v4i x3 = ((const v4i*)src)[3];
        v4i w;
        w.x = (int)pack4(x0); w.y = (int)pack4(x1);
        w.z = (int)pack4(x2); w.w = (int)pack4(x3);
        *(v4i*)(dst + p * 16) = w;
    }
}

// ---- pack B: int32 [G][K][N] -> int8 blocked [g][nt][kt][swz(128n x 64k)] ----
__global__ __launch_bounds__(256)
void pack_b(const int* __restrict__ B, unsigned char* __restrict__ Bp)
{
    const int b  = blockIdx.x;
    const int g  = b >> 11;
    const int nt = (b >> 6) & 31;
    const int kt = b & 63;
    const int t  = threadIdx.x;
    const int k0 = (t >> 5) * 8;
    const int n4 = (t & 31) * 4;

    const int* src = B + (size_t)g * KK * NN + (size_t)(kt * 64 + k0) * NN
                       + nt * 128 + n4;
    v4i r[8];
    #pragma unroll
    for (int j = 0; j < 8; ++j)
        r[j] = *(const v4i*)(src + (size_t)j * NN);

    unsigned char* dst = Bp + (size_t)b * TILE_BYTES;
    #pragma unroll
    for (int n = 0; n < 4; ++n) {
        unsigned lo = (r[0][n] & 255) | ((r[1][n] & 255) << 8) |
                      ((r[2][n] & 255) << 16) | ((unsigned)r[3][n] << 24);
        unsigned hi = (r[4][n] & 255) | ((r[5][n] & 255) << 8) |
                      ((r[6][n] & 255) << 16) | ((unsigned)r[7][n] << 24);
        unsigned long long wv = (unsigned long long)lo |
                                ((unsigned long long)hi << 32);
        *(unsigned long long*)(dst + swz(n4 + n, k0)) = wv;
    }
}

// One K-step: optionally prefetch next tile's fragments, MFMA current.
// All register names passed explicitly (static indexing only).
#define KSTEP(AFC, AFH, BFC, AFN, AFN2, BFN, APN, BPN, DO_PF)             \
    do {                                                                   \
        if (DO_PF) {                                                       \
            _Pragma("unroll") for (int n = 0; n < 4; ++n)                  \
                BFN[n] = *(const v4i*)((BPN) + boff[n]);                   \
            _Pragma("unroll") for (int m = 0; m < 4; ++m)                  \
                AFN[m] = *(const v4i*)((APN) + aoff[m]);                   \
        }                                                                  \
        _Pragma("unroll") for (int m = 0; m < 4; ++m)                      \
            _Pragma("unroll") for (int n = 0; n < 4; ++n)                  \
                acc[m][n] = __builtin_amdgcn_mfma_i32_16x16x64_i8(         \
                    AFC[m], BFC[n], acc[m][n], 0, 0, 0);                   \
        if (DO_PF) {                                                       \
            _Pragma("unroll") for (int m = 0; m < 4; ++m)                  \
                AFN2[m] = *(const v4i*)((APN) + aoff[m + 4]);              \
        }                                                                  \
        _Pragma("unroll") for (int m = 0; m < 4; ++m)                      \
            _Pragma("unroll") for (int n = 0; n < 4; ++n)                  \
                acc[m + 4][n] = __builtin_amdgcn_mfma_i32_16x16x64_i8(     \
                    AFH[m], BFC[n], acc[m + 4][n], 0, 0, 0);               \
    } while (0)

// ---- main GEMM: 256x256, 8 waves, NO LDS, NO barriers: fragments loaded
// directly from the packed layout into VGPRs, register double-buffered ----
__global__ __launch_bounds__(512, 2)
void gg_i8d(const unsigned char* __restrict__ Ap,
            const unsigned char* __restrict__ Bp,
            const float* __restrict__ scale, const float* __restrict__ pts,
            const int* __restrict__ glist, float* __restrict__ out)
{
    const int t    = threadIdx.x;
    const int lane = t & 63;
    const int wid  = t >> 6;       // 0..7
    const int wr   = wid >> 2;     // 0..1  (M split)
    const int wc   = wid & 3;      // 0..3  (N split)

    // XCD-aware swizzle (512 % 8 == 0 -> bijective); XCD x owns group x's
    // 4 MB A-slab (L2-resident).
    const int nwg  = gridDim.x;
    const int cpx  = nwg >> 3;
    const int bid  = blockIdx.x;
    const int swzb = (bid & 7) * cpx + (bid >> 3);
    const int mtc  = swzb >> 4;    // 0..31
    const int ntc  = swzb & 15;    // 0..15
    const int brow = mtc * BM;
    const int bcol = ntc * BN;

    int g = 0;
    #pragma unroll
    for (int i = 0; i < NG - 1; ++i)
        if (brow >= glist[i]) g = i + 1;

    // per-lane 32-bit fragment offsets (fixed); K advances a uniform base ptr
    const int fr = lane & 15;
    const int kh = lane >> 4;
    int aoff[8], boff[4];
    #pragma unroll
    for (int m = 0; m < 8; ++m) {
        const int row = wr * 128 + m * 16 + fr;
        aoff[m] = (2 * mtc + (row >> 7)) * (NKT * TILE_BYTES)
                + swz(row & 127, kh * 16);
    }
    #pragma unroll
    for (int n = 0; n < 4; ++n) {
        const int row = wc * 64 + n * 16 + fr;
        boff[n] = (g * B_TILES_N + 2 * ntc + (row >> 7)) * (NKT * TILE_BYTES)
                + swz(row & 127, kh * 16);
    }

    v4i acc[8][4];
    #pragma unroll
    for (int i = 0; i < 8; ++i)
        #pragma unroll
        for (int j = 0; j < 4; ++j)
            acc[i][j] = (v4i){0, 0, 0, 0};

    const unsigned char* ap = Ap;      // + kt*TILE_BYTES (uniform, SGPR)
    const unsigned char* bp = Bp;

    v4i afc[4], afh[4], bfc[4], afn[4], afn2[4], bfn[4];

    // prologue: tile 0 fragments
    #pragma unroll
    for (int n = 0; n < 4; ++n) bfc[n] = *(const v4i*)(bp + boff[n]);
    #pragma unroll
    for (int m = 0; m < 4; ++m) afc[m] = *(const v4i*)(ap + aoff[m]);
    #pragma unroll
    for (int m = 0; m < 4; ++m) afh[m] = *(const v4i*)(ap + aoff[m + 4]);

    #pragma unroll 1
    for (int it = 0; it < NKT / 2; ++it) {
        // consume kt=2it, prefetch kt=2it+1 (always exists)
        KSTEP(afc, afh, bfc, afn, afn2, bfn,
              ap + TILE_BYTES, bp + TILE_BYTES, true);
        // consume kt=2it+1, prefetch kt=2it+2 (except last)
        const bool pf2 = (it < NKT / 2 - 1);
        KSTEP(afn, afn2, bfn, afc, afh, bfc,
              ap + 2 * TILE_BYTES, bp + 2 * TILE_BYTES, pf2);
        ap += 2 * TILE_BYTES;
        bp += 2 * TILE_BYTES;
    }

    // ---- epilogue: dequant + store ----
    #pragma unroll
    for (int mi = 0; mi < 8; ++mi) {
        const int r0 = brow + wr * 128 + mi * 16 + (lane >> 4) * 4;
        float pt[4];
        #pragma unroll
        for (int e = 0; e < 4; ++e) pt[e] = pts[r0 + e];
        #pragma unroll
        for (int ni = 0; ni < 4; ++ni) {
            const int col = bcol + wc * 64 + ni * 16 + (lane & 15);
            const float sc = scale[g * NN + col];
            #pragma unroll
            for (int e = 0; e < 4; ++e)
                out[(size_t)(r0 + e) * NN + col] = (float)acc[mi][ni][e] * sc * pt[e];
        }
    }
}

// ---- fused fallback (only if ws too small; round-1 verified kernel) ----
__global__ __launch_bounds__(256, 2)
void gg_i8(const int* __restrict__ A, const int* __restrict__ B,
           const float* __restrict__ scale, const float* __restrict__ pts,
           const int* __restrict__ glist, float* __restrict__ out)
{
    __shared__ unsigned char Ab[2][128 * 64];
    __shared__ unsigned char Bb[2][128 * 64];

    const int t    = threadIdx.x;
    const int lane = t & 63;
    const int wid  = t >> 6;
    const int wr   = wid >> 1;
    const int wc   = wid & 1;

    const int nwg  = gridDim.x;
    const int cpx  = nwg >> 3;
    const int bid  = blockIdx.x;
    const int swzb = (bid & 7) * cpx + (bid >> 3);
    const int mt   = swzb >> 5;
    const int nt   = swzb & 31;
    const int brow = mt * 128;
    const int bcol = nt * 128;

    int g = 0;
    #pragma unroll
    for (int i = 0; i < NG - 1; ++i)
        if (brow >= glist[i]) g = i + 1;
    const int* Bg = B + (size_t)g * (KK * NN);

    const int arow = t >> 4;
    const int acol = (t & 15) * 4;
    const int bkq = (t >> 5) * 8;
    const int bnq = (t & 31) * 4;

    const int* aP = A  + (size_t)(brow + arow) * KK + acol;
    const int* bP = Bg + (size_t)bkq * NN + bcol + bnq;

    int awoff[8];
    #pragma unroll
    for (int i = 0; i < 8; ++i) awoff[i] = swz(arow + i * 16, acol);
    int bwoff[4];
    #pragma unroll
    for (int ni = 0; ni < 4; ++ni) bwoff[ni] = swz(bnq + ni, bkq);

    const int fr = lane & 15;
    const int kh = lane >> 4;
    int afoff[4], bfoff[4];
    #pragma unroll
    for (int mi = 0; mi < 4; ++mi) afoff[mi] = swz(wr * 64 + mi * 16 + fr, kh * 16);
    #pragma unroll
    for (int ni = 0; ni < 4; ++ni) bfoff[ni] = swz(wc * 64 + ni * 16 + fr, kh * 16);

    v4i aL[8], bL[8];
    v4i acc[4][4];
    #pragma unroll
    for (int i = 0; i < 4; ++i)
        #pragma unroll
        for (int j = 0; j < 4; ++j)
            acc[i][j] = (v4i){0, 0, 0, 0};

    auto stage_load = [&](int kt) {
        const int* ap = aP + kt * 64;
        #pragma unroll
        for (int i = 0; i < 8; ++i)
            aL[i] = *(const v4i*)(ap + (size_t)i * 16 * KK);
        const int* bp = bP + (size_t)kt * 64 * NN;
        #pragma unroll
        for (int j = 0; j < 8; ++j)
            bL[j] = *(const v4i*)(bp + (size_t)j * NN);
    };

    auto stage_write = [&](int buf) {
        #pragma unroll
        for (int i = 0; i < 8; ++i)
            *(unsigned*)(&Ab[buf][awoff[i]]) = pack4(aL[i]);
        #pragma unroll
        for (int ni = 0; ni < 4; ++ni) {
            unsigned lo = (bL[0][ni] & 255) | ((bL[1][ni] & 255) << 8) |
                          ((bL[2][ni] & 255) << 16) | ((unsigned)bL[3][ni] << 24);
            unsigned hi = (bL[4][ni] & 255) | ((bL[5][ni] & 255) << 8) |
                          ((bL[6][ni] & 255) << 16) | ((unsigned)bL[7][ni] << 24);
            unsigned long long w = (unsigned long long)lo |
                                   ((unsigned long long)hi << 32);
            *(unsigned long long*)(&Bb[buf][bwoff[ni]]) = w;
        }
    };

    stage_load(0);
    stage_write(0);
    __syncthreads();

    int cur = 0;
    for (int kt = 0; kt < NKT; ++kt) {
        const bool pf = (kt + 1 < NKT);
        if (pf) stage_load(kt + 1);

        v4i af[4], bfr[4];
        #pragma unroll
        for (int mi = 0; mi < 4; ++mi)
            af[mi] = *(const v4i*)(&Ab[cur][afoff[mi]]);
        #pragma unroll
        for (int ni = 0; ni < 4; ++ni)
            bfr[ni] = *(const v4i*)(&Bb[cur][bfoff[ni]]);

        #pragma unroll
        for (int mi = 0; mi < 4; ++mi)
            #pragma unroll
            for (int ni = 0; ni < 4; ++ni)
                acc[mi][ni] = __builtin_amdgcn_mfma_i32_16x16x64_i8(
                    af[mi], bfr[ni], acc[mi][ni], 0, 0, 0);

        if (pf) stage_write(cur ^ 1);
        __syncthreads();
        cur ^= 1;
    }

    #pragma unroll
    for (int mi = 0; mi < 4; ++mi) {
        const int r0 = brow + wr * 64 + mi * 16 + (lane >> 4) * 4;
        #pragma unroll
        for (int ni = 0; ni < 4; ++ni) {
            const int col = bcol + wc * 64 + ni * 16 + (lane & 15);
            const float sc = scale[g * NN + col];
            #pragma unroll
            for (int e = 0; e < 4; ++e) {
                const int r = r0 + e;
                out[(size_t)r * NN + col] = (float)acc[mi][ni][e] * sc * pts[r];
            }
        }
    }
}

extern "C" void kernel_launch(void* const* d_in, const int* in_sizes, int n_in,
                              void* d_out, int out_size, void* d_ws, size_t ws_size,
                              hipStream_t stream) {
    const int*   A     = (const int*)d_in[0];
    const int*   B     = (const int*)d_in[1];
    const float* scale = (const float*)d_in[2];
    const float* pts   = (const float*)d_in[3];
    const int*   glist = (const int*)d_in[4];
    float*       out   = (float*)d_out;

    if (ws_size >= AP_BYTES + BP_BYTES) {
        unsigned char* Ap = (unsigned char*)d_ws;
        unsigned char* Bp = Ap + AP_BYTES;
        pack_a<<<dim3(A_TILES_M * NKT), 256, 0, stream>>>(A, Ap);
        pack_b<<<dim3(NG * B_TILES_N * NKT), 256, 0, stream>>>(B, Bp);
        gg_i8d<<<dim3((MM / BM) * (NN / BN)), 512, 0, stream>>>(
            Ap, Bp, scale, pts, glist, out);
    } else {
        gg_i8<<<dim3((MM / 128) * (NN / 128)), 256, 0, stream>>>(
            A, B, scale, pts, glist, out);
    }
}

// Round 8
// 384.747 us; speedup vs baseline: 1.2090x; 1.2090x over previous
//
#include <hip/hip_runtime.h>

typedef int v4i __attribute__((ext_vector_type(4)));

#define MM 8192
#define KK 4096
#define NN 4096
#define NG 8
#define TILE_BYTES 8192          // packed B tile: 128 n-rows x 64 k-bytes, swizzled
#define NKT 64                   // K / 64
#define A_TILES_M 64             // M / 128 (fallback kernel geometry)
#define B_TILES_N 32             // N / 128
#define AP_BYTES ((size_t)512 * NKT * 1024)                  // 32 MB (frag-major)
#define BP_BYTES ((size_t)NG * B_TILES_N * NKT * TILE_BYTES) // 128 MB

#define BM 256
#define BN 256

// XOR swizzle within a 128-row x 64-byte tile (16B-slot granular). (B + fallback)
__device__ __forceinline__ int swz(int row, int c) {
    int line = row >> 1;
    int s = ((((row & 1) << 2) | (c >> 4)) ^ ((row >> 2) & 7));
    return line * 128 + s * 16 + (c & 15);
}

__device__ __forceinline__ unsigned pack4(v4i v) {
    return (v.x & 255) | ((v.y & 255) << 8) | ((v.z & 255) << 16) |
           ((unsigned)v.w & 0xff000000u ? ((unsigned)v.w << 24) : ((unsigned)v.w << 24));
}

__device__ __forceinline__ unsigned pack4b(v4i v) {
    return (v.x & 255) | ((v.y & 255) << 8) | ((v.z & 255) << 16) |
           ((unsigned)v.w << 24);
}

__device__ __forceinline__ void gload16(const void* g, void* l) {
    __builtin_amdgcn_global_load_lds(
        (const __attribute__((address_space(1))) void*)g,
        (__attribute__((address_space(3))) void*)l, 16, 0, 0);
}

// ---- pack A: int32 [M][K] -> int8 FRAGMENT-MAJOR:
// frag (mi 0..511, kt 0..63) is 1 KB at ((mi*64)+kt)*1024; byte l*16+j holds
// A[mi*16 + (l&15)][kt*64 + (l>>4)*16 + j]  (exact MFMA A-operand lane order)
__global__ __launch_bounds__(256)
void pack_a(const int* __restrict__ A, unsigned char* __restrict__ Ap)
{
    const int mi  = blockIdx.x;          // 0..511
    const int t   = threadIdx.x;
    const int l   = t & 63;
    const int kt4 = t >> 6;              // 0..3
    const int row = mi * 16 + (l & 15);
    const int kc  = (l >> 4) * 16;       // int32 index within the 64-k tile
    const int* src0 = A + (size_t)row * KK + kc;
    unsigned char* dst0 = Ap + (size_t)mi * 64 * 1024 + l * 16;

    #pragma unroll
    for (int j = 0; j < 16; ++j) {
        const int kt = kt4 * 16 + j;
        const int* src = src0 + kt * 64;
        v4i x0 = ((const v4i*)src)[0];
        v4i x1 = ((const v4i*)src)[1];
        v4i x2 = ((const v4i*)src)[2];
        v4i x3 = ((const v4i*)src)[3];
        v4i w;
        w.x = (int)pack4b(x0); w.y = (int)pack4b(x1);
        w.z = (int)pack4b(x2); w.w = (int)pack4b(x3);
        *(v4i*)(dst0 + (size_t)kt * 1024) = w;
    }
}

// ---- pack B: int32 [G][K][N] -> int8 blocked [g][nt][kt][swz(128n x 64k)] ----
__global__ __launch_bounds__(256)
void pack_b(const int* __restrict__ B, unsigned char* __restrict__ Bp)
{
    const int b  = blockIdx.x;
    const int g  = b >> 11;
    const int nt = (b >> 6) & 31;
    const int kt = b & 63;
    const int t  = threadIdx.x;
    const int k0 = (t >> 5) * 8;
    const int n4 = (t & 31) * 4;

    const int* src = B + (size_t)g * KK * NN + (size_t)(kt * 64 + k0) * NN
                       + nt * 128 + n4;
    v4i r[8];
    #pragma unroll
    for (int j = 0; j < 8; ++j)
        r[j] = *(const v4i*)(src + (size_t)j * NN);

    unsigned char* dst = Bp + (size_t)b * TILE_BYTES;
    #pragma unroll
    for (int n = 0; n < 4; ++n) {
        unsigned lo = (r[0][n] & 255) | ((r[1][n] & 255) << 8) |
                      ((r[2][n] & 255) << 16) | ((unsigned)r[3][n] << 24);
        unsigned hi = (r[4][n] & 255) | ((r[5][n] & 255) << 8) |
                      ((r[6][n] & 255) << 16) | ((unsigned)r[7][n] << 24);
        unsigned long long wv = (unsigned long long)lo |
                                ((unsigned long long)hi << 32);
        *(unsigned long long*)(dst + swz(n4 + n, k0)) = wv;
    }
}

#define MFMA16(AF)                                                         \
    do {                                                                   \
        _Pragma("unroll") for (int m = 0; m < 8; ++m)                      \
            _Pragma("unroll") for (int n = 0; n < 4; ++n)                  \
                acc[m][n] = __builtin_amdgcn_mfma_i32_16x16x64_i8(         \
                    AF[m], bf[n], acc[m][n], 0, 0, 0);                     \
    } while (0)

// ---- main GEMM: 256x256, 8 waves. A: frag-major global->reg (coalesced,
// L1-shared, reg double-buffered, no LDS). B: global_load_lds double-buffer,
// one __syncthreads per K-tile. ----
__global__ __launch_bounds__(512, 2)
void gg_i8f(const unsigned char* __restrict__ Ap,
            const unsigned char* __restrict__ Bp,
            const float* __restrict__ scale, const float* __restrict__ pts,
            const int* __restrict__ glist, float* __restrict__ out)
{
    __shared__ unsigned char Blds[2 * 16384];   // 32 KB

    const int t    = threadIdx.x;
    const int lane = t & 63;
    const int wid  = t >> 6;       // 0..7
    const int wr   = wid >> 2;     // 0..1  (M split)
    const int wc   = wid & 3;      // 0..3  (N split)

    // XCD-aware swizzle (512 % 8 == 0 -> bijective)
    const int nwg  = gridDim.x;
    const int cpx  = nwg >> 3;
    const int bid  = blockIdx.x;
    const int swzb = (bid & 7) * cpx + (bid >> 3);
    const int mtc  = swzb >> 4;    // 0..31
    const int ntc  = swzb & 15;    // 0..15
    const int brow = mtc * BM;
    const int bcol = ntc * BN;

    int g = 0;
    #pragma unroll
    for (int i = 0; i < NG - 1; ++i)
        if (brow >= glist[i]) g = i + 1;

    // A frag base: wave's 8 m-frags are mi = mtc*16 + wr*8 + m
    const unsigned char* abase =
        Ap + (size_t)(mtc * 16 + wr * 8) * 64 * 1024 + lane * 16;

    const unsigned char* bpg0 = Bp + ((size_t)g * B_TILES_N + 2 * ntc)     * NKT * TILE_BYTES;
    const unsigned char* bpg1 = Bp + ((size_t)g * B_TILES_N + 2 * ntc + 1) * NKT * TILE_BYTES;

    const int ldsB = wid * 1024;           // wave-uniform chunk base
    const int gchB = ldsB + lane * 16;     // per-lane global offset

    // B fragment LDS offsets (within one 16 KB buffer)
    const int fr = lane & 15;
    const int kh = lane >> 4;
    int bfoff[4];
    #pragma unroll
    for (int n = 0; n < 4; ++n) {
        const int row = wc * 64 + n * 16 + fr;
        bfoff[n] = (row >> 7) * 8192 + swz(row & 127, kh * 16);
    }

    v4i acc[8][4];
    #pragma unroll
    for (int i = 0; i < 8; ++i)
        #pragma unroll
        for (int j = 0; j < 4; ++j)
            acc[i][j] = (v4i){0, 0, 0, 0};

    auto stageB = [&](int ktn) {
        unsigned char* lb = &Blds[(ktn & 1) * 16384];
        const size_t tk = (size_t)ktn * TILE_BYTES;
        gload16(bpg0 + tk + gchB, lb + ldsB);
        gload16(bpg1 + tk + gchB, lb + 8192 + ldsB);
    };

    v4i aC[8], aN[8], bf[4];

    // prologue: B(0) staged; A(0) fragments to regs
    stageB(0);
    #pragma unroll
    for (int m = 0; m < 8; ++m)
        aC[m] = *(const v4i*)(abase + (size_t)(m * 64) * 1024);
    __syncthreads();   // drains B(0) DMA + A(0) loads

    #pragma unroll 1
    for (int it = 0; it < NKT / 2; ++it) {
        const int k0 = 2 * it;

        // ---- kt = k0 (B buf 0) ----
        stageB(k0 + 1);                       // k0+1 <= 63 always
        #pragma unroll
        for (int n = 0; n < 4; ++n)
            bf[n] = *(const v4i*)(&Blds[0] + bfoff[n]);
        #pragma unroll
        for (int m = 0; m < 8; ++m)           // prefetch A(k0+1)
            aN[m] = *(const v4i*)(abase + (size_t)(m * 64 + k0 + 1) * 1024);
        __builtin_amdgcn_s_setprio(1);
        MFMA16(aC);
        __builtin_amdgcn_s_setprio(0);
        __syncthreads();                      // B(k0+1) resident after this

        // ---- kt = k0+1 (B buf 1) ----
        const bool more = (k0 + 2 < NKT);
        if (more) stageB(k0 + 2);
        #pragma unroll
        for (int n = 0; n < 4; ++n)
            bf[n] = *(const v4i*)(&Blds[16384] + bfoff[n]);
        if (more) {
            #pragma unroll
            for (int m = 0; m < 8; ++m)       // prefetch A(k0+2)
                aC[m] = *(const v4i*)(abase + (size_t)(m * 64 + k0 + 2) * 1024);
        }
        __builtin_amdgcn_s_setprio(1);
        MFMA16(aN);
        __builtin_amdgcn_s_setprio(0);
        __syncthreads();
    }

    // ---- epilogue: dequant + store ----
    #pragma unroll
    for (int mi = 0; mi < 8; ++mi) {
        const int r0 = brow + wr * 128 + mi * 16 + (lane >> 4) * 4;
        float pt[4];
        #pragma unroll
        for (int e = 0; e < 4; ++e) pt[e] = pts[r0 + e];
        #pragma unroll
        for (int ni = 0; ni < 4; ++ni) {
            const int col = bcol + wc * 64 + ni * 16 + (lane & 15);
            const float sc = scale[g * NN + col];
            #pragma unroll
            for (int e = 0; e < 4; ++e)
                out[(size_t)(r0 + e) * NN + col] = (float)acc[mi][ni][e] * sc * pt[e];
        }
    }
}

// ---- fused fallback (only if ws too small; round-1 verified kernel) ----
__global__ __launch_bounds__(256, 2)
void gg_i8(const int* __restrict__ A, const int* __restrict__ B,
           const float* __restrict__ scale, const float* __restrict__ pts,
           const int* __restrict__ glist, float* __restrict__ out)
{
    __shared__ unsigned char Ab[2][128 * 64];
    __shared__ unsigned char Bb[2][128 * 64];

    const int t    = threadIdx.x;
    const int lane = t & 63;
    const int wid  = t >> 6;
    const int wr   = wid >> 1;
    const int wc   = wid & 1;

    const int nwg  = gridDim.x;
    const int cpx  = nwg >> 3;
    const int bid  = blockIdx.x;
    const int swzb = (bid & 7) * cpx + (bid >> 3);
    const int mt   = swzb >> 5;
    const int nt   = swzb & 31;
    const int brow = mt * 128;
    const int bcol = nt * 128;

    int g = 0;
    #pragma unroll
    for (int i = 0; i < NG - 1; ++i)
        if (brow >= glist[i]) g = i + 1;
    const int* Bg = B + (size_t)g * (KK * NN);

    const int arow = t >> 4;
    const int acol = (t & 15) * 4;
    const int bkq = (t >> 5) * 8;
    const int bnq = (t & 31) * 4;

    const int* aP = A  + (size_t)(brow + arow) * KK + acol;
    const int* bP = Bg + (size_t)bkq * NN + bcol + bnq;

    int awoff[8];
    #pragma unroll
    for (int i = 0; i < 8; ++i) awoff[i] = swz(arow + i * 16, acol);
    int bwoff[4];
    #pragma unroll
    for (int ni = 0; ni < 4; ++ni) bwoff[ni] = swz(bnq + ni, bkq);

    const int fr = lane & 15;
    const int kh = lane >> 4;
    int afoff[4], bfoff[4];
    #pragma unroll
    for (int mi = 0; mi < 4; ++mi) afoff[mi] = swz(wr * 64 + mi * 16 + fr, kh * 16);
    #pragma unroll
    for (int ni = 0; ni < 4; ++ni) bfoff[ni] = swz(wc * 64 + ni * 16 + fr, kh * 16);

    v4i aL[8], bL[8];
    v4i acc[4][4];
    #pragma unroll
    for (int i = 0; i < 4; ++i)
        #pragma unroll
        for (int j = 0; j < 4; ++j)
            acc[i][j] = (v4i){0, 0, 0, 0};

    auto stage_load = [&](int kt) {
        const int* ap = aP + kt * 64;
        #pragma unroll
        for (int i = 0; i < 8; ++i)
            aL[i] = *(const v4i*)(ap + (size_t)i * 16 * KK);
        const int* bp = bP + (size_t)kt * 64 * NN;
        #pragma unroll
        for (int j = 0; j < 8; ++j)
            bL[j] = *(const v4i*)(bp + (size_t)j * NN);
    };

    auto stage_write = [&](int buf) {
        #pragma unroll
        for (int i = 0; i < 8; ++i)
            *(unsigned*)(&Ab[buf][awoff[i]]) = pack4b(aL[i]);
        #pragma unroll
        for (int ni = 0; ni < 4; ++ni) {
            unsigned lo = (bL[0][ni] & 255) | ((bL[1][ni] & 255) << 8) |
                          ((bL[2][ni] & 255) << 16) | ((unsigned)bL[3][ni] << 24);
            unsigned hi = (bL[4][ni] & 255) | ((bL[5][ni] & 255) << 8) |
                          ((bL[6][ni] & 255) << 16) | ((unsigned)bL[7][ni] << 24);
            unsigned long long w = (unsigned long long)lo |
                                   ((unsigned long long)hi << 32);
            *(unsigned long long*)(&Bb[buf][bwoff[ni]]) = w;
        }
    };

    stage_load(0);
    stage_write(0);
    __syncthreads();

    int cur = 0;
    for (int kt = 0; kt < NKT; ++kt) {
        const bool pf = (kt + 1 < NKT);
        if (pf) stage_load(kt + 1);

        v4i af[4], bfr[4];
        #pragma unroll
        for (int mi = 0; mi < 4; ++mi)
            af[mi] = *(const v4i*)(&Ab[cur][afoff[mi]]);
        #pragma unroll
        for (int ni = 0; ni < 4; ++ni)
            bfr[ni] = *(const v4i*)(&Bb[cur][bfoff[ni]]);

        #pragma unroll
        for (int mi = 0; mi < 4; ++mi)
            #pragma unroll
            for (int ni = 0; ni < 4; ++ni)
                acc[mi][ni] = __builtin_amdgcn_mfma_i32_16x16x64_i8(
                    af[mi], bfr[ni], acc[mi][ni], 0, 0, 0);

        if (pf) stage_write(cur ^ 1);
        __syncthreads();
        cur ^= 1;
    }

    #pragma unroll
    for (int mi = 0; mi < 4; ++mi) {
        const int r0 = brow + wr * 64 + mi * 16 + (lane >> 4) * 4;
        #pragma unroll
        for (int ni = 0; ni < 4; ++ni) {
            const int col = bcol + wc * 64 + ni * 16 + (lane & 15);
            const float sc = scale[g * NN + col];
            #pragma unroll
            for (int e = 0; e < 4; ++e) {
                const int r = r0 + e;
                out[(size_t)r * NN + col] = (float)acc[mi][ni][e] * sc * pts[r];
            }
        }
    }
}

extern "C" void kernel_launch(void* const* d_in, const int* in_sizes, int n_in,
                              void* d_out, int out_size, void* d_ws, size_t ws_size,
                              hipStream_t stream) {
    const int*   A     = (const int*)d_in[0];
    const int*   B     = (const int*)d_in[1];
    const float* scale = (const float*)d_in[2];
    const float* pts   = (const float*)d_in[3];
    const int*   glist = (const int*)d_in[4];
    float*       out   = (float*)d_out;

    if (ws_size >= AP_BYTES + BP_BYTES) {
        unsigned char* Ap = (unsigned char*)d_ws;
        unsigned char* Bp = Ap + AP_BYTES;
        pack_a<<<dim3(512), 256, 0, stream>>>(A, Ap);
        pack_b<<<dim3(NG * B_TILES_N * NKT), 256, 0, stream>>>(B, Bp);
        gg_i8f<<<dim3((MM / BM) * (NN / BN)), 512, 0, stream>>>(
            Ap, Bp, scale, pts, glist, out);
    } else {
        gg_i8<<<dim3((MM / 128) * (NN / 128)), 256, 0, stream>>>(
            A, B, scale, pts, glist, out);
    }
}

// Round 9
// 325.246 us; speedup vs baseline: 1.4302x; 1.1829x over previous
//
#include <hip/hip_runtime.h>

typedef int v4i __attribute__((ext_vector_type(4)));

#define MM 8192
#define KK 4096
#define NN 4096
#define NG 8
#define TILE_BYTES 8192          // packed tile: 128 rows x 64 k-bytes, swizzled
#define NKT 64                   // K / 64
#define A_TILES_M 64             // M / 128
#define B_TILES_N 32             // N / 128
#define AP_BYTES ((size_t)A_TILES_M * NKT * TILE_BYTES)      // 32 MB
#define BP_BYTES ((size_t)NG * B_TILES_N * NKT * TILE_BYTES) // 128 MB

// GEMM geometry (256^2 tile, 8 waves, 4-deep LDS pipeline)
#define BM 256
#define BN 256
#define NBUF 4
#define ABYTES 16384             // 256 rows x 64 k
#define BBYTES 16384
#define BUFBYTES (ABYTES + BBYTES)   // 32 KB; x4 = 128 KB LDS

// XOR swizzle within a 128-row x 64-byte tile (16B-slot granular).
__device__ __forceinline__ int swz(int row, int c) {
    int line = row >> 1;
    int s = ((((row & 1) << 2) | (c >> 4)) ^ ((row >> 2) & 7));
    return line * 128 + s * 16 + (c & 15);
}

__device__ __forceinline__ unsigned pack4(v4i v) {
    return (v.x & 255) | ((v.y & 255) << 8) | ((v.z & 255) << 16) |
           ((unsigned)v.w << 24);
}

__device__ __forceinline__ void gload16(const void* g, void* l) {
    __builtin_amdgcn_global_load_lds(
        (const __attribute__((address_space(1))) void*)g,
        (__attribute__((address_space(3))) void*)l, 16, 0, 0);
}

// ---- pack A: int32 [M][K] -> int8 blocked [mt][kt][swz(128x64)] ----
__global__ __launch_bounds__(256)
void pack_a(const int* __restrict__ A, unsigned char* __restrict__ Ap)
{
    const int b  = blockIdx.x;
    const int mt = b >> 6;
    const int kt = b & 63;
    const int t  = threadIdx.x;
    unsigned char* dst = Ap + (size_t)b * TILE_BYTES;

    #pragma unroll
    for (int i = 0; i < 2; ++i) {
        const int p    = t + i * 256;       // 16B output slot index
        const int line = p >> 3, sl = p & 7;
        const int h    = (line >> 1) & 7;
        const int y    = sl ^ h;            // inverse swizzle
        const int row  = 2 * line + (y >> 2);
        const int c16  = y & 3;
        const int* src = A + (size_t)(mt * 128 + row) * KK + kt * 64 + c16 * 16;
        v4i x0 = ((const v4i*)src)[0];
        v4i x1 = ((const v4i*)src)[1];
        v4i x2 = ((const v4i*)src)[2];
        v4i x3 = ((const v4i*)src)[3];
        v4i w;
        w.x = (int)pack4(x0); w.y = (int)pack4(x1);
        w.z = (int)pack4(x2); w.w = (int)pack4(x3);
        *(v4i*)(dst + p * 16) = w;
    }
}

// ---- pack B: int32 [G][K][N] -> int8 blocked [g][nt][kt][swz(128n x 64k)]
// v2: assemble the swizzled tile in LDS, dump linearly (coalesced 16B/lane
// writes) — removes the 8B scattered partial-line writes of v1. Output
// bytes are bit-identical to v1. ----
__global__ __launch_bounds__(256)
void pack_b(const int* __restrict__ B, unsigned char* __restrict__ Bp)
{
    __shared__ unsigned char tile[TILE_BYTES];

    const int b  = blockIdx.x;
    const int g  = b >> 11;
    const int nt = (b >> 6) & 31;
    const int kt = b & 63;
    const int t  = threadIdx.x;
    const int k0 = (t >> 5) * 8;
    const int n4 = (t & 31) * 4;

    const int* src = B + (size_t)g * KK * NN + (size_t)(kt * 64 + k0) * NN
                       + nt * 128 + n4;
    v4i r[8];
    #pragma unroll
    for (int j = 0; j < 8; ++j)
        r[j] = *(const v4i*)(src + (size_t)j * NN);

    #pragma unroll
    for (int n = 0; n < 4; ++n) {
        unsigned lo = (r[0][n] & 255) | ((r[1][n] & 255) << 8) |
                      ((r[2][n] & 255) << 16) | ((unsigned)r[3][n] << 24);
        unsigned hi = (r[4][n] & 255) | ((r[5][n] & 255) << 8) |
                      ((r[6][n] & 255) << 16) | ((unsigned)r[7][n] << 24);
        unsigned long long wv = (unsigned long long)lo |
                                ((unsigned long long)hi << 32);
        *(unsigned long long*)(&tile[swz(n4 + n, k0)]) = wv;
    }
    __syncthreads();

    const v4i* s = (const v4i*)tile;
    v4i* d = (v4i*)(Bp + (size_t)b * TILE_BYTES);
    d[t]       = s[t];
    d[t + 256] = s[t + 256];
}

#define BAR() do { __builtin_amdgcn_s_barrier(); \
                   asm volatile("" ::: "memory"); } while (0)

// ---- main GEMM (best verified: round-4 bench, 313.7 us total):
// 256x256 tile, 8 waves, 4-phase per 2 K-tiles, counted vmcnt ----
__global__ __launch_bounds__(512, 2)
void gg_i8p3(const unsigned char* __restrict__ Ap,
             const unsigned char* __restrict__ Bp,
             const float* __restrict__ scale, const float* __restrict__ pts,
             const int* __restrict__ glist, float* __restrict__ out)
{
    __shared__ unsigned char lds[NBUF * BUFBYTES];   // 128 KB

    const int t    = threadIdx.x;
    const int lane = t & 63;
    const int wid  = t >> 6;       // 0..7
    const int wr   = wid >> 2;     // 0..1  (M split)
    const int wc   = wid & 3;      // 0..3  (N split)

    // XCD-aware swizzle (512 % 8 == 0 -> bijective)
    const int nwg  = gridDim.x;
    const int cpx  = nwg >> 3;
    const int bid  = blockIdx.x;
    const int swzb = (bid & 7) * cpx + (bid >> 3);
    const int mtc  = swzb >> 4;    // 0..31
    const int ntc  = swzb & 15;    // 0..15
    const int brow = mtc * BM;
    const int bcol = ntc * BN;

    int g = 0;
    #pragma unroll
    for (int i = 0; i < NG - 1; ++i)
        if (brow >= glist[i]) g = i + 1;

    const unsigned char* apg0 = Ap + (size_t)(2 * mtc)     * NKT * TILE_BYTES;
    const unsigned char* apg1 = Ap + (size_t)(2 * mtc + 1) * NKT * TILE_BYTES;
    const unsigned char* bpg0 = Bp + ((size_t)g * B_TILES_N + 2 * ntc)     * NKT * TILE_BYTES;
    const unsigned char* bpg1 = Bp + ((size_t)g * B_TILES_N + 2 * ntc + 1) * NKT * TILE_BYTES;

    const int ldsch = wid * 1024;          // wave-uniform chunk base
    const int gch   = ldsch + lane * 16;   // per-lane global offset

    // fragment LDS offsets (within one buffer)
    const int fr = lane & 15;
    const int kh = lane >> 4;
    int afoff[8], bfoff[4];
    #pragma unroll
    for (int m = 0; m < 8; ++m) {
        const int row = wr * 128 + m * 16 + fr;
        afoff[m] = (row >> 7) * 8192 + swz(row & 127, kh * 16);
    }
    #pragma unroll
    for (int n = 0; n < 4; ++n) {
        const int row = wc * 64 + n * 16 + fr;
        bfoff[n] = ABYTES + (row >> 7) * 8192 + swz(row & 127, kh * 16);
    }

    v4i acc[8][4];
    #pragma unroll
    for (int i = 0; i < 8; ++i)
        #pragma unroll
        for (int j = 0; j < 4; ++j)
            acc[i][j] = (v4i){0, 0, 0, 0};

    // one K-tile stage = 4 x gload16 per thread (A0,A1,B0,B1 chunks)
    auto stageA = [&](int kt) {
        const size_t tk = (size_t)kt * TILE_BYTES;
        unsigned char* la = &lds[(kt & 3) * BUFBYTES];
        gload16(apg0 + tk + gch, la + ldsch);
        gload16(apg1 + tk + gch, la + 8192 + ldsch);
    };
    auto stageB = [&](int kt) {
        const size_t tk = (size_t)kt * TILE_BYTES;
        unsigned char* la = &lds[(kt & 3) * BUFBYTES];
        gload16(bpg0 + tk + gch, la + ABYTES + ldsch);
        gload16(bpg1 + tk + gch, la + ABYTES + 8192 + ldsch);
    };

    // prologue: tiles 0,1,2 in flight (12 loads/thread)
    stageA(0); stageB(0);
    stageA(1); stageB(1);
    stageA(2); stageB(2);

    #pragma unroll 1
    for (int it = 0; it < NKT / 2; ++it) {
        const int t0 = 2 * it;
        const unsigned char* lb0 = &lds[(t0 & 3) * BUFBYTES];
        const unsigned char* lb1 = &lds[((t0 + 1) & 3) * BUFBYTES];
        const bool pf01 = (t0 + 3 < NKT);   // stage(t0+3) split over ph0/ph1
        const bool pf23 = (t0 + 4 < NKT);   // stage(t0+4) split over ph2/ph3

        v4i af[4], af2[4], bf[4];

        // ---------- phase 0: tile t0, rows m0-3 ----------
        if (it < NKT / 2 - 1) asm volatile("s_waitcnt vmcnt(8)" ::: "memory");
        else                  asm volatile("s_waitcnt vmcnt(4)" ::: "memory");
        BAR();

        #pragma unroll
        for (int m = 0; m < 4; ++m) af[m] = *(const v4i*)(lb0 + afoff[m]);
        #pragma unroll
        for (int n = 0; n < 4; ++n) bf[n] = *(const v4i*)(lb0 + bfoff[n]);
        if (pf01) stageA(t0 + 3);

        __builtin_amdgcn_s_setprio(1);
        #pragma unroll
        for (int m = 0; m < 4; ++m)
            #pragma unroll
            for (int n = 0; n < 4; ++n)
                acc[m][n] = __builtin_amdgcn_mfma_i32_16x16x64_i8(
                    af[m], bf[n], acc[m][n], 0, 0, 0);
        __builtin_amdgcn_s_setprio(0);

        // ---------- phase 1: tile t0, rows m4-7 ----------
        BAR();

        #pragma unroll
        for (int m = 0; m < 4; ++m) af2[m] = *(const v4i*)(lb0 + afoff[m + 4]);
        if (pf01) stageB(t0 + 3);

        __builtin_amdgcn_s_setprio(1);
        #pragma unroll
        for (int m = 0; m < 4; ++m)
            #pragma unroll
            for (int n = 0; n < 4; ++n)
                acc[m + 4][n] = __builtin_amdgcn_mfma_i32_16x16x64_i8(
                    af2[m], bf[n], acc[m + 4][n], 0, 0, 0);
        __builtin_amdgcn_s_setprio(0);

        // ---------- phase 2: tile t0+1, rows m0-3 ----------
        if (it < NKT / 2 - 1) asm volatile("s_waitcnt vmcnt(8)" ::: "memory");
        else                  asm volatile("s_waitcnt vmcnt(0)" ::: "memory");
        BAR();

        #pragma unroll
        for (int m = 0; m < 4; ++m) af[m] = *(const v4i*)(lb1 + afoff[m]);
        #pragma unroll
        for (int n = 0; n < 4; ++n) bf[n] = *(const v4i*)(lb1 + bfoff[n]);
        if (pf23) stageA(t0 + 4);

        __builtin_amdgcn_s_setprio(1);
        #pragma unroll
        for (int m = 0; m < 4; ++m)
            #pragma unroll
            for (int n = 0; n < 4; ++n)
                acc[m][n] = __builtin_amdgcn_mfma_i32_16x16x64_i8(
                    af[m], bf[n], acc[m][n], 0, 0, 0);
        __builtin_amdgcn_s_setprio(0);

        // ---------- phase 3: tile t0+1, rows m4-7 ----------
        BAR();

        #pragma unroll
        for (int m = 0; m < 4; ++m) af2[m] = *(const v4i*)(lb1 + afoff[m + 4]);
        if (pf23) stageB(t0 + 4);

        __builtin_amdgcn_s_setprio(1);
        #pragma unroll
        for (int m = 0; m < 4; ++m)
            #pragma unroll
            for (int n = 0; n < 4; ++n)
                acc[m + 4][n] = __builtin_amdgcn_mfma_i32_16x16x64_i8(
                    af2[m], bf[n], acc[m + 4][n], 0, 0, 0);
        __builtin_amdgcn_s_setprio(0);
    }

    // ---- epilogue: dequant + store ----
    #pragma unroll
    for (int mi = 0; mi < 8; ++mi) {
        const int r0 = brow + wr * 128 + mi * 16 + (lane >> 4) * 4;
        float pt[4];
        #pragma unroll
        for (int e = 0; e < 4; ++e) pt[e] = pts[r0 + e];
        #pragma unroll
        for (int ni = 0; ni < 4; ++ni) {
            const int col = bcol + wc * 64 + ni * 16 + (lane & 15);
            const float sc = scale[g * NN + col];
            #pragma unroll
            for (int e = 0; e < 4; ++e)
                out[(size_t)(r0 + e) * NN + col] = (float)acc[mi][ni][e] * sc * pt[e];
        }
    }
}

// ---- fused fallback (only if ws too small; round-1 verified kernel) ----
__global__ __launch_bounds__(256, 2)
void gg_i8(const int* __restrict__ A, const int* __restrict__ B,
           const float* __restrict__ scale, const float* __restrict__ pts,
           const int* __restrict__ glist, float* __restrict__ out)
{
    __shared__ unsigned char Ab[2][128 * 64];
    __shared__ unsigned char Bb[2][128 * 64];

    const int t    = threadIdx.x;
    const int lane = t & 63;
    const int wid  = t >> 6;
    const int wr   = wid >> 1;
    const int wc   = wid & 1;

    const int nwg  = gridDim.x;
    const int cpx  = nwg >> 3;
    const int bid  = blockIdx.x;
    const int swzb = (bid & 7) * cpx + (bid >> 3);
    const int mt   = swzb >> 5;
    const int nt   = swzb & 31;
    const int brow = mt * 128;
    const int bcol = nt * 128;

    int g = 0;
    #pragma unroll
    for (int i = 0; i < NG - 1; ++i)
        if (brow >= glist[i]) g = i + 1;
    const int* Bg = B + (size_t)g * (KK * NN);

    const int arow = t >> 4;
    const int acol = (t & 15) * 4;
    const int bkq = (t >> 5) * 8;
    const int bnq = (t & 31) * 4;

    const int* aP = A  + (size_t)(brow + arow) * KK + acol;
    const int* bP = Bg + (size_t)bkq * NN + bcol + bnq;

    int awoff[8];
    #pragma unroll
    for (int i = 0; i < 8; ++i) awoff[i] = swz(arow + i * 16, acol);
    int bwoff[4];
    #pragma unroll
    for (int ni = 0; ni < 4; ++ni) bwoff[ni] = swz(bnq + ni, bkq);

    const int fr = lane & 15;
    const int kh = lane >> 4;
    int afoff[4], bfoff[4];
    #pragma unroll
    for (int mi = 0; mi < 4; ++mi) afoff[mi] = swz(wr * 64 + mi * 16 + fr, kh * 16);
    #pragma unroll
    for (int ni = 0; ni < 4; ++ni) bfoff[ni] = swz(wc * 64 + ni * 16 + fr, kh * 16);

    v4i aL[8], bL[8];
    v4i acc[4][4];
    #pragma unroll
    for (int i = 0; i < 4; ++i)
        #pragma unroll
        for (int j = 0; j < 4; ++j)
            acc[i][j] = (v4i){0, 0, 0, 0};

    auto stage_load = [&](int kt) {
        const int* ap = aP + kt * 64;
        #pragma unroll
        for (int i = 0; i < 8; ++i)
            aL[i] = *(const v4i*)(ap + (size_t)i * 16 * KK);
        const int* bp = bP + (size_t)kt * 64 * NN;
        #pragma unroll
        for (int j = 0; j < 8; ++j)
            bL[j] = *(const v4i*)(bp + (size_t)j * NN);
    };

    auto stage_write = [&](int buf) {
        #pragma unroll
        for (int i = 0; i < 8; ++i)
            *(unsigned*)(&Ab[buf][awoff[i]]) = pack4(aL[i]);
        #pragma unroll
        for (int ni = 0; ni < 4; ++ni) {
            unsigned lo = (bL[0][ni] & 255) | ((bL[1][ni] & 255) << 8) |
                          ((bL[2][ni] & 255) << 16) | ((unsigned)bL[3][ni] << 24);
            unsigned hi = (bL[4][ni] & 255) | ((bL[5][ni] & 255) << 8) |
                          ((bL[6][ni] & 255) << 16) | ((unsigned)bL[7][ni] << 24);
            unsigned long long w = (unsigned long long)lo |
                                   ((unsigned long long)hi << 32);
            *(unsigned long long*)(&Bb[buf][bwoff[ni]]) = w;
        }
    };

    stage_load(0);
    stage_write(0);
    __syncthreads();

    int cur = 0;
    for (int kt = 0; kt < NKT; ++kt) {
        const bool pf = (kt + 1 < NKT);
        if (pf) stage_load(kt + 1);

        v4i af[4], bfr[4];
        #pragma unroll
        for (int mi = 0; mi < 4; ++mi)
            af[mi] = *(const v4i*)(&Ab[cur][afoff[mi]]);
        #pragma unroll
        for (int ni = 0; ni < 4; ++ni)
            bfr[ni] = *(const v4i*)(&Bb[cur][bfoff[ni]]);

        #pragma unroll
        for (int mi = 0; mi < 4; ++mi)
            #pragma unroll
            for (int ni = 0; ni < 4; ++ni)
                acc[mi][ni] = __builtin_amdgcn_mfma_i32_16x16x64_i8(
                    af[mi], bfr[ni], acc[mi][ni], 0, 0, 0);

        if (pf) stage_write(cur ^ 1);
        __syncthreads();
        cur ^= 1;
    }

    #pragma unroll
    for (int mi = 0; mi < 4; ++mi) {
        const int r0 = brow + wr * 64 + mi * 16 + (lane >> 4) * 4;
        #pragma unroll
        for (int ni = 0; ni < 4; ++ni) {
            const int col = bcol + wc * 64 + ni * 16 + (lane & 15);
            const float sc = scale[g * NN + col];
            #pragma unroll
            for (int e = 0; e < 4; ++e) {
                const int r = r0 + e;
                out[(size_t)r * NN + col] = (float)acc[mi][ni][e] * sc * pts[r];
            }
        }
    }
}

extern "C" void kernel_launch(void* const* d_in, const int* in_sizes, int n_in,
                              void* d_out, int out_size, void* d_ws, size_t ws_size,
                              hipStream_t stream) {
    const int*   A     = (const int*)d_in[0];
    const int*   B     = (const int*)d_in[1];
    const float* scale = (const float*)d_in[2];
    const float* pts   = (const float*)d_in[3];
    const int*   glist = (const int*)d_in[4];
    float*       out   = (float*)d_out;

    if (ws_size >= AP_BYTES + BP_BYTES) {
        unsigned char* Ap = (unsigned char*)d_ws;
        unsigned char* Bp = Ap + AP_BYTES;
        pack_a<<<dim3(A_TILES_M * NKT), 256, 0, stream>>>(A, Ap);
        pack_b<<<dim3(NG * B_TILES_N * NKT), 256, 0, stream>>>(B, Bp);
        gg_i8p3<<<dim3((MM / BM) * (NN / BN)), 512, 0, stream>>>(
            Ap, Bp, scale, pts, glist, out);
    } else {
        gg_i8<<<dim3((MM / 128) * (NN / 128)), 256, 0, stream>>>(
            A, B, scale, pts, glist, out);
    }
}

// Round 10
// 319.246 us; speedup vs baseline: 1.4571x; 1.0188x over previous
//
#include <hip/hip_runtime.h>

typedef int v4i  __attribute__((ext_vector_type(4)));
typedef int v16i __attribute__((ext_vector_type(16)));

#define MM 8192
#define KK 4096
#define NN 4096
#define NG 8
#define TILE_BYTES 8192          // packed tile: 128 rows x 64 k-bytes, swizzled
#define NKT 64                   // K / 64
#define A_TILES_M 64             // M / 128
#define B_TILES_N 32             // N / 128
#define AP_BYTES ((size_t)A_TILES_M * NKT * TILE_BYTES)      // 32 MB
#define BP_BYTES ((size_t)NG * B_TILES_N * NKT * TILE_BYTES) // 128 MB

// GEMM geometry (256^2 tile, 8 waves, 4-deep LDS pipeline)
#define BM 256
#define BN 256
#define NBUF 4
#define ABYTES 16384             // 256 rows x 64 k
#define BBYTES 16384
#define BUFBYTES (ABYTES + BBYTES)   // 32 KB; x4 = 128 KB LDS

// XOR swizzle within a 128-row x 64-byte tile (16B-slot granular).
__device__ __forceinline__ int swz(int row, int c) {
    int line = row >> 1;
    int s = ((((row & 1) << 2) | (c >> 4)) ^ ((row >> 2) & 7));
    return line * 128 + s * 16 + (c & 15);
}

__device__ __forceinline__ unsigned pack4(v4i v) {
    return (v.x & 255) | ((v.y & 255) << 8) | ((v.z & 255) << 16) |
           ((unsigned)v.w << 24);
}

__device__ __forceinline__ void gload16(const void* g, void* l) {
    __builtin_amdgcn_global_load_lds(
        (const __attribute__((address_space(1))) void*)g,
        (__attribute__((address_space(3))) void*)l, 16, 0, 0);
}

// ---- pack A: int32 [M][K] -> int8 blocked [mt][kt][swz(128x64)] ----
__global__ __launch_bounds__(256)
void pack_a(const int* __restrict__ A, unsigned char* __restrict__ Ap)
{
    const int b  = blockIdx.x;
    const int mt = b >> 6;
    const int kt = b & 63;
    const int t  = threadIdx.x;
    unsigned char* dst = Ap + (size_t)b * TILE_BYTES;

    #pragma unroll
    for (int i = 0; i < 2; ++i) {
        const int p    = t + i * 256;       // 16B output slot index
        const int line = p >> 3, sl = p & 7;
        const int h    = (line >> 1) & 7;
        const int y    = sl ^ h;            // inverse swizzle
        const int row  = 2 * line + (y >> 2);
        const int c16  = y & 3;
        const int* src = A + (size_t)(mt * 128 + row) * KK + kt * 64 + c16 * 16;
        v4i x0 = ((const v4i*)src)[0];
        v4i x1 = ((const v4i*)src)[1];
        v4i x2 = ((const v4i*)src)[2];
        v4i x3 = ((const v4i*)src)[3];
        v4i w;
        w.x = (int)pack4(x0); w.y = (int)pack4(x1);
        w.z = (int)pack4(x2); w.w = (int)pack4(x3);
        *(v4i*)(dst + p * 16) = w;
    }
}

// ---- pack B (v1, best-verified): int32 [G][K][N] -> int8 blocked
// [g][nt][kt][swz(128n x 64k)] ----
__global__ __launch_bounds__(256)
void pack_b(const int* __restrict__ B, unsigned char* __restrict__ Bp)
{
    const int b  = blockIdx.x;
    const int g  = b >> 11;
    const int nt = (b >> 6) & 31;
    const int kt = b & 63;
    const int t  = threadIdx.x;
    const int k0 = (t >> 5) * 8;
    const int n4 = (t & 31) * 4;

    const int* src = B + (size_t)g * KK * NN + (size_t)(kt * 64 + k0) * NN
                       + nt * 128 + n4;
    v4i r[8];
    #pragma unroll
    for (int j = 0; j < 8; ++j)
        r[j] = *(const v4i*)(src + (size_t)j * NN);

    unsigned char* dst = Bp + (size_t)b * TILE_BYTES;
    #pragma unroll
    for (int n = 0; n < 4; ++n) {
        unsigned lo = (r[0][n] & 255) | ((r[1][n] & 255) << 8) |
                      ((r[2][n] & 255) << 16) | ((unsigned)r[3][n] << 24);
        unsigned hi = (r[4][n] & 255) | ((r[5][n] & 255) << 8) |
                      ((r[6][n] & 255) << 16) | ((unsigned)r[7][n] << 24);
        unsigned long long wv = (unsigned long long)lo |
                                ((unsigned long long)hi << 32);
        *(unsigned long long*)(dst + swz(n4 + n, k0)) = wv;
    }
}

#define BAR() do { __builtin_amdgcn_s_barrier(); \
                   asm volatile("" ::: "memory"); } while (0)

// ---- main GEMM: 256x256 tile, 8 waves, R4 4-phase skeleton, but with
// mfma_i32_32x32x32_i8 (half the MFMA instructions, +12% MFMA ceiling).
// Operand map: lane l = row (l&31), 16 k-bytes at kw*32 + (l>>5)*16.
// C/D map (HW-verified 32x32): col=lane&31, row=(r&3)+8*(r>>2)+4*(lane>>5).
__global__ __launch_bounds__(512, 2)
void gg_i8p6(const unsigned char* __restrict__ Ap,
             const unsigned char* __restrict__ Bp,
             const float* __restrict__ scale, const float* __restrict__ pts,
             const int* __restrict__ glist, float* __restrict__ out)
{
    __shared__ unsigned char lds[NBUF * BUFBYTES];   // 128 KB

    const int t    = threadIdx.x;
    const int lane = t & 63;
    const int wid  = t >> 6;       // 0..7
    const int wr   = wid >> 2;     // 0..1  (M split)
    const int wc   = wid & 3;      // 0..3  (N split)

    // XCD-aware swizzle (512 % 8 == 0 -> bijective)
    const int nwg  = gridDim.x;
    const int cpx  = nwg >> 3;
    const int bid  = blockIdx.x;
    const int swzb = (bid & 7) * cpx + (bid >> 3);
    const int mtc  = swzb >> 4;    // 0..31
    const int ntc  = swzb & 15;    // 0..15
    const int brow = mtc * BM;
    const int bcol = ntc * BN;

    int g = 0;
    #pragma unroll
    for (int i = 0; i < NG - 1; ++i)
        if (brow >= glist[i]) g = i + 1;

    const unsigned char* apg0 = Ap + (size_t)(2 * mtc)     * NKT * TILE_BYTES;
    const unsigned char* apg1 = Ap + (size_t)(2 * mtc + 1) * NKT * TILE_BYTES;
    const unsigned char* bpg0 = Bp + ((size_t)g * B_TILES_N + 2 * ntc)     * NKT * TILE_BYTES;
    const unsigned char* bpg1 = Bp + ((size_t)g * B_TILES_N + 2 * ntc + 1) * NKT * TILE_BYTES;

    const int ldsch = wid * 1024;          // wave-uniform chunk base
    const int gch   = ldsch + lane * 16;   // per-lane global offset

    // fragment LDS offsets: [frag][k-window]
    const int l31 = lane & 31;
    const int lhi = lane >> 5;
    int afoff[4][2], bfoff[2][2];
    #pragma unroll
    for (int m = 0; m < 4; ++m)
        #pragma unroll
        for (int kw = 0; kw < 2; ++kw) {
            const int row = wr * 128 + m * 32 + l31;
            afoff[m][kw] = (row >> 7) * 8192 + swz(row & 127, kw * 32 + lhi * 16);
        }
    #pragma unroll
    for (int n = 0; n < 2; ++n)
        #pragma unroll
        for (int kw = 0; kw < 2; ++kw) {
            const int row = wc * 64 + n * 32 + l31;
            bfoff[n][kw] = ABYTES + (row >> 7) * 8192 + swz(row & 127, kw * 32 + lhi * 16);
        }

    v16i acc[4][2];
    #pragma unroll
    for (int i = 0; i < 4; ++i)
        #pragma unroll
        for (int j = 0; j < 2; ++j)
            #pragma unroll
            for (int r = 0; r < 16; ++r)
                acc[i][j][r] = 0;

    // one K-tile stage = 4 x gload16 per thread (A0,A1,B0,B1 chunks)
    auto stageA = [&](int kt) {
        const size_t tk = (size_t)kt * TILE_BYTES;
        unsigned char* la = &lds[(kt & 3) * BUFBYTES];
        gload16(apg0 + tk + gch, la + ldsch);
        gload16(apg1 + tk + gch, la + 8192 + ldsch);
    };
    auto stageB = [&](int kt) {
        const size_t tk = (size_t)kt * TILE_BYTES;
        unsigned char* la = &lds[(kt & 3) * BUFBYTES];
        gload16(bpg0 + tk + gch, la + ABYTES + ldsch);
        gload16(bpg1 + tk + gch, la + ABYTES + 8192 + ldsch);
    };

    // prologue: tiles 0,1,2 in flight (12 loads/thread)
    stageA(0); stageB(0);
    stageA(1); stageB(1);
    stageA(2); stageB(2);

    #pragma unroll 1
    for (int it = 0; it < NKT / 2; ++it) {
        const int t0 = 2 * it;
        const unsigned char* lb0 = &lds[(t0 & 3) * BUFBYTES];
        const unsigned char* lb1 = &lds[((t0 + 1) & 3) * BUFBYTES];
        const bool pf01 = (t0 + 3 < NKT);
        const bool pf23 = (t0 + 4 < NKT);

        v4i af[2][2], af2[2][2], bf[2][2];

        // ---------- phase 0: tile t0, m-frags 0-1 ----------
        if (it < NKT / 2 - 1) asm volatile("s_waitcnt vmcnt(8)" ::: "memory");
        else                  asm volatile("s_waitcnt vmcnt(4)" ::: "memory");
        BAR();

        #pragma unroll
        for (int m = 0; m < 2; ++m)
            #pragma unroll
            for (int kw = 0; kw < 2; ++kw)
                af[m][kw] = *(const v4i*)(lb0 + afoff[m][kw]);
        #pragma unroll
        for (int n = 0; n < 2; ++n)
            #pragma unroll
            for (int kw = 0; kw < 2; ++kw)
                bf[n][kw] = *(const v4i*)(lb0 + bfoff[n][kw]);
        if (pf01) stageA(t0 + 3);

        __builtin_amdgcn_s_setprio(1);
        #pragma unroll
        for (int m = 0; m < 2; ++m)
            #pragma unroll
            for (int n = 0; n < 2; ++n)
                #pragma unroll
                for (int kw = 0; kw < 2; ++kw)
                    acc[m][n] = __builtin_amdgcn_mfma_i32_32x32x32_i8(
                        af[m][kw], bf[n][kw], acc[m][n], 0, 0, 0);
        __builtin_amdgcn_s_setprio(0);

        // ---------- phase 1: tile t0, m-frags 2-3 ----------
        BAR();

        #pragma unroll
        for (int m = 0; m < 2; ++m)
            #pragma unroll
            for (int kw = 0; kw < 2; ++kw)
                af2[m][kw] = *(const v4i*)(lb0 + afoff[m + 2][kw]);
        if (pf01) stageB(t0 + 3);

        __builtin_amdgcn_s_setprio(1);
        #pragma unroll
        for (int m = 0; m < 2; ++m)
            #pragma unroll
            for (int n = 0; n < 2; ++n)
                #pragma unroll
                for (int kw = 0; kw < 2; ++kw)
                    acc[m + 2][n] = __builtin_amdgcn_mfma_i32_32x32x32_i8(
                        af2[m][kw], bf[n][kw], acc[m + 2][n], 0, 0, 0);
        __builtin_amdgcn_s_setprio(0);

        // ---------- phase 2: tile t0+1, m-frags 0-1 ----------
        if (it < NKT / 2 - 1) asm volatile("s_waitcnt vmcnt(8)" ::: "memory");
        else                  asm volatile("s_waitcnt vmcnt(0)" ::: "memory");
        BAR();

        #pragma unroll
        for (int m = 0; m < 2; ++m)
            #pragma unroll
            for (int kw = 0; kw < 2; ++kw)
                af[m][kw] = *(const v4i*)(lb1 + afoff[m][kw]);
        #pragma unroll
        for (int n = 0; n < 2; ++n)
            #pragma unroll
            for (int kw = 0; kw < 2; ++kw)
                bf[n][kw] = *(const v4i*)(lb1 + bfoff[n][kw]);
        if (pf23) stageA(t0 + 4);

        __builtin_amdgcn_s_setprio(1);
        #pragma unroll
        for (int m = 0; m < 2; ++m)
            #pragma unroll
            for (int n = 0; n < 2; ++n)
                #pragma unroll
                for (int kw = 0; kw < 2; ++kw)
                    acc[m][n] = __builtin_amdgcn_mfma_i32_32x32x32_i8(
                        af[m][kw], bf[n][kw], acc[m][n], 0, 0, 0);
        __builtin_amdgcn_s_setprio(0);

        // ---------- phase 3: tile t0+1, m-frags 2-3 ----------
        BAR();

        #pragma unroll
        for (int m = 0; m < 2; ++m)
            #pragma unroll
            for (int kw = 0; kw < 2; ++kw)
                af2[m][kw] = *(const v4i*)(lb1 + afoff[m + 2][kw]);
        if (pf23) stageB(t0 + 4);

        __builtin_amdgcn_s_setprio(1);
        #pragma unroll
        for (int m = 0; m < 2; ++m)
            #pragma unroll
            for (int n = 0; n < 2; ++n)
                #pragma unroll
                for (int kw = 0; kw < 2; ++kw)
                    acc[m + 2][n] = __builtin_amdgcn_mfma_i32_32x32x32_i8(
                        af2[m][kw], bf[n][kw], acc[m + 2][n], 0, 0, 0);
        __builtin_amdgcn_s_setprio(0);
    }

    // ---- epilogue: dequant + store (verified 32x32 C/D map) ----
    #pragma unroll
    for (int m = 0; m < 4; ++m) {
        const int rowb = brow + wr * 128 + m * 32 + 4 * lhi;
        float pt[16];
        #pragma unroll
        for (int r = 0; r < 16; ++r)
            pt[r] = pts[rowb + (r & 3) + 8 * (r >> 2)];
        #pragma unroll
        for (int n = 0; n < 2; ++n) {
            const int col = bcol + wc * 64 + n * 32 + l31;
            const float sc = scale[g * NN + col];
            #pragma unroll
            for (int r = 0; r < 16; ++r) {
                const int row = rowb + (r & 3) + 8 * (r >> 2);
                out[(size_t)row * NN + col] = (float)acc[m][n][r] * sc * pt[r];
            }
        }
    }
}

// ---- fused fallback (only if ws too small; round-1 verified kernel) ----
__global__ __launch_bounds__(256, 2)
void gg_i8(const int* __restrict__ A, const int* __restrict__ B,
           const float* __restrict__ scale, const float* __restrict__ pts,
           const int* __restrict__ glist, float* __restrict__ out)
{
    __shared__ unsigned char Ab[2][128 * 64];
    __shared__ unsigned char Bb[2][128 * 64];

    const int t    = threadIdx.x;
    const int lane = t & 63;
    const int wid  = t >> 6;
    const int wr   = wid >> 1;
    const int wc   = wid & 1;

    const int nwg  = gridDim.x;
    const int cpx  = nwg >> 3;
    const int bid  = blockIdx.x;
    const int swzb = (bid & 7) * cpx + (bid >> 3);
    const int mt   = swzb >> 5;
    const int nt   = swzb & 31;
    const int brow = mt * 128;
    const int bcol = nt * 128;

    int g = 0;
    #pragma unroll
    for (int i = 0; i < NG - 1; ++i)
        if (brow >= glist[i]) g = i + 1;
    const int* Bg = B + (size_t)g * (KK * NN);

    const int arow = t >> 4;
    const int acol = (t & 15) * 4;
    const int bkq = (t >> 5) * 8;
    const int bnq = (t & 31) * 4;

    const int* aP = A  + (size_t)(brow + arow) * KK + acol;
    const int* bP = Bg + (size_t)bkq * NN + bcol + bnq;

    int awoff[8];
    #pragma unroll
    for (int i = 0; i < 8; ++i) awoff[i] = swz(arow + i * 16, acol);
    int bwoff[4];
    #pragma unroll
    for (int ni = 0; ni < 4; ++ni) bwoff[ni] = swz(bnq + ni, bkq);

    const int fr = lane & 15;
    const int kh = lane >> 4;
    int afoff[4], bfoff[4];
    #pragma unroll
    for (int mi = 0; mi < 4; ++mi) afoff[mi] = swz(wr * 64 + mi * 16 + fr, kh * 16);
    #pragma unroll
    for (int ni = 0; ni < 4; ++ni) bfoff[ni] = swz(wc * 64 + ni * 16 + fr, kh * 16);

    v4i aL[8], bL[8];
    v4i acc[4][4];
    #pragma unroll
    for (int i = 0; i < 4; ++i)
        #pragma unroll
        for (int j = 0; j < 4; ++j)
            acc[i][j] = (v4i){0, 0, 0, 0};

    auto stage_load = [&](int kt) {
        const int* ap = aP + kt * 64;
        #pragma unroll
        for (int i = 0; i < 8; ++i)
            aL[i] = *(const v4i*)(ap + (size_t)i * 16 * KK);
        const int* bp = bP + (size_t)kt * 64 * NN;
        #pragma unroll
        for (int j = 0; j < 8; ++j)
            bL[j] = *(const v4i*)(bp + (size_t)j * NN);
    };

    auto stage_write = [&](int buf) {
        #pragma unroll
        for (int i = 0; i < 8; ++i)
            *(unsigned*)(&Ab[buf][awoff[i]]) = pack4(aL[i]);
        #pragma unroll
        for (int ni = 0; ni < 4; ++ni) {
            unsigned lo = (bL[0][ni] & 255) | ((bL[1][ni] & 255) << 8) |
                          ((bL[2][ni] & 255) << 16) | ((unsigned)bL[3][ni] << 24);
            unsigned hi = (bL[4][ni] & 255) | ((bL[5][ni] & 255) << 8) |
                          ((bL[6][ni] & 255) << 16) | ((unsigned)bL[7][ni] << 24);
            unsigned long long w = (unsigned long long)lo |
                                   ((unsigned long long)hi << 32);
            *(unsigned long long*)(&Bb[buf][bwoff[ni]]) = w;
        }
    };

    stage_load(0);
    stage_write(0);
    __syncthreads();

    int cur = 0;
    for (int kt = 0; kt < NKT; ++kt) {
        const bool pf = (kt + 1 < NKT);
        if (pf) stage_load(kt + 1);

        v4i af[4], bfr[4];
        #pragma unroll
        for (int mi = 0; mi < 4; ++mi)
            af[mi] = *(const v4i*)(&Ab[cur][afoff[mi]]);
        #pragma unroll
        for (int ni = 0; ni < 4; ++ni)
            bfr[ni] = *(const v4i*)(&Bb[cur][bfoff[ni]]);

        #pragma unroll
        for (int mi = 0; mi < 4; ++mi)
            #pragma unroll
            for (int ni = 0; ni < 4; ++ni)
                acc[mi][ni] = __builtin_amdgcn_mfma_i32_16x16x64_i8(
                    af[mi], bfr[ni], acc[mi][ni], 0, 0, 0);

        if (pf) stage_write(cur ^ 1);
        __syncthreads();
        cur ^= 1;
    }

    #pragma unroll
    for (int mi = 0; mi < 4; ++mi) {
        const int r0 = brow + wr * 64 + mi * 16 + (lane >> 4) * 4;
        #pragma unroll
        for (int ni = 0; ni < 4; ++ni) {
            const int col = bcol + wc * 64 + ni * 16 + (lane & 15);
            const float sc = scale[g * NN + col];
            #pragma unroll
            for (int e = 0; e < 4; ++e) {
                const int r = r0 + e;
                out[(size_t)r * NN + col] = (float)acc[mi][ni][e] * sc * pts[r];
            }
        }
    }
}

extern "C" void kernel_launch(void* const* d_in, const int* in_sizes, int n_in,
                              void* d_out, int out_size, void* d_ws, size_t ws_size,
                              hipStream_t stream) {
    const int*   A     = (const int*)d_in[0];
    const int*   B     = (const int*)d_in[1];
    const float* scale = (const float*)d_in[2];
    const float* pts   = (const float*)d_in[3];
    const int*   glist = (const int*)d_in[4];
    float*       out   = (float*)d_out;

    if (ws_size >= AP_BYTES + BP_BYTES) {
        unsigned char* Ap = (unsigned char*)d_ws;
        unsigned char* Bp = Ap + AP_BYTES;
        pack_a<<<dim3(A_TILES_M * NKT), 256, 0, stream>>>(A, Ap);
        pack_b<<<dim3(NG * B_TILES_N * NKT), 256, 0, stream>>>(B, Bp);
        gg_i8p6<<<dim3((MM / BM) * (NN / BN)), 512, 0, stream>>>(
            Ap, Bp, scale, pts, glist, out);
    } else {
        gg_i8<<<dim3((MM / 128) * (NN / 128)), 256, 0, stream>>>(
            A, B, scale, pts, glist, out);
    }
}

// Round 11
// 318.079 us; speedup vs baseline: 1.4624x; 1.0037x over previous
//
#include <hip/hip_runtime.h>

typedef int v4i __attribute__((ext_vector_type(4)));

#define MM 8192
#define KK 4096
#define NN 4096
#define NG 8
#define TILE_BYTES 8192          // packed tile: 128 rows x 64 k-bytes, swizzled
#define NKT 64                   // K / 64
#define A_TILES_M 64             // M / 128
#define B_TILES_N 32             // N / 128
#define AP_BYTES ((size_t)A_TILES_M * NKT * TILE_BYTES)      // 32 MB
#define BP_BYTES ((size_t)NG * B_TILES_N * NKT * TILE_BYTES) // 128 MB

// GEMM geometry: 128x256 tile, 8 waves (2M x 4N), 3-buffer pipeline,
// 72 KB LDS -> 2 blocks/CU (4 waves/SIMD)
#define BM 128
#define BN 256
#define NBUF 3
#define ABYTES 8192              // 128 rows x 64 k
#define BBYTES 16384             // 256 rows x 64 k
#define BUFBYTES (ABYTES + BBYTES)   // 24 KB; x3 = 72 KB LDS

// XOR swizzle within a 128-row x 64-byte tile (16B-slot granular).
__device__ __forceinline__ int swz(int row, int c) {
    int line = row >> 1;
    int s = ((((row & 1) << 2) | (c >> 4)) ^ ((row >> 2) & 7));
    return line * 128 + s * 16 + (c & 15);
}

__device__ __forceinline__ unsigned pack4(v4i v) {
    return (v.x & 255) | ((v.y & 255) << 8) | ((v.z & 255) << 16) |
           ((unsigned)v.w << 24);
}

__device__ __forceinline__ void gload16(const void* g, void* l) {
    __builtin_amdgcn_global_load_lds(
        (const __attribute__((address_space(1))) void*)g,
        (__attribute__((address_space(3))) void*)l, 16, 0, 0);
}

// ---- pack A: int32 [M][K] -> int8 blocked [mt][kt][swz(128x64)] ----
__global__ __launch_bounds__(256)
void pack_a(const int* __restrict__ A, unsigned char* __restrict__ Ap)
{
    const int b  = blockIdx.x;
    const int mt = b >> 6;
    const int kt = b & 63;
    const int t  = threadIdx.x;
    unsigned char* dst = Ap + (size_t)b * TILE_BYTES;

    #pragma unroll
    for (int i = 0; i < 2; ++i) {
        const int p    = t + i * 256;       // 16B output slot index
        const int line = p >> 3, sl = p & 7;
        const int h    = (line >> 1) & 7;
        const int y    = sl ^ h;            // inverse swizzle
        const int row  = 2 * line + (y >> 2);
        const int c16  = y & 3;
        const int* src = A + (size_t)(mt * 128 + row) * KK + kt * 64 + c16 * 16;
        v4i x0 = ((const v4i*)src)[0];
        v4i x1 = ((const v4i*)src)[1];
        v4i x2 = ((const v4i*)src)[2];
        v4i x3 = ((const v4i*)src)[3];
        v4i w;
        w.x = (int)pack4(x0); w.y = (int)pack4(x1);
        w.z = (int)pack4(x2); w.w = (int)pack4(x3);
        *(v4i*)(dst + p * 16) = w;
    }
}

// ---- pack B (v1, best-verified): int32 [G][K][N] -> int8 blocked
// [g][nt][kt][swz(128n x 64k)] ----
__global__ __launch_bounds__(256)
void pack_b(const int* __restrict__ B, unsigned char* __restrict__ Bp)
{
    const int b  = blockIdx.x;
    const int g  = b >> 11;
    const int nt = (b >> 6) & 31;
    const int kt = b & 63;
    const int t  = threadIdx.x;
    const int k0 = (t >> 5) * 8;
    const int n4 = (t & 31) * 4;

    const int* src = B + (size_t)g * KK * NN + (size_t)(kt * 64 + k0) * NN
                       + nt * 128 + n4;
    v4i r[8];
    #pragma unroll
    for (int j = 0; j < 8; ++j)
        r[j] = *(const v4i*)(src + (size_t)j * NN);

    unsigned char* dst = Bp + (size_t)b * TILE_BYTES;
    #pragma unroll
    for (int n = 0; n < 4; ++n) {
        unsigned lo = (r[0][n] & 255) | ((r[1][n] & 255) << 8) |
                      ((r[2][n] & 255) << 16) | ((unsigned)r[3][n] << 24);
        unsigned hi = (r[4][n] & 255) | ((r[5][n] & 255) << 8) |
                      ((r[6][n] & 255) << 16) | ((unsigned)r[7][n] << 24);
        unsigned long long wv = (unsigned long long)lo |
                                ((unsigned long long)hi << 32);
        *(unsigned long long*)(dst + swz(n4 + n, k0)) = wv;
    }
}

#define BAR() do { __builtin_amdgcn_s_barrier(); \
                   asm volatile("" ::: "memory"); } while (0)

// ---- main GEMM: 128x256 tile, 8 waves, 2 blocks/CU, R4-style 2-phase/kt
// skeleton with counted vmcnt(3) (A=1 + B=2 loads per kt per thread) ----
__global__ __launch_bounds__(512, 4)
void gg_i8o(const unsigned char* __restrict__ Ap,
            const unsigned char* __restrict__ Bp,
            const float* __restrict__ scale, const float* __restrict__ pts,
            const int* __restrict__ glist, float* __restrict__ out)
{
    __shared__ unsigned char lds[NBUF * BUFBYTES];   // 72 KB

    const int t    = threadIdx.x;
    const int lane = t & 63;
    const int wid  = t >> 6;       // 0..7
    const int wr   = wid >> 2;     // 0..1  (M split: 64 rows each)
    const int wc   = wid & 3;      // 0..3  (N split: 64 cols each)

    // XCD-aware swizzle (1024 % 8 == 0 -> bijective); XCD x gets
    // mtc in [8x, 8x+8) = exactly group x's 1024-row A slab.
    const int nwg  = gridDim.x;
    const int cpx  = nwg >> 3;           // 128
    const int bid  = blockIdx.x;
    const int swzb = (bid & 7) * cpx + (bid >> 3);
    const int mtc  = swzb >> 4;          // 0..63 (128-row tiles)
    const int ntc  = swzb & 15;          // 0..15 (256-col tiles)
    const int brow = mtc * BM;
    const int bcol = ntc * BN;

    int g = 0;
    #pragma unroll
    for (int i = 0; i < NG - 1; ++i)
        if (brow >= glist[i]) g = i + 1;

    const unsigned char* apg  = Ap + (size_t)mtc * NKT * TILE_BYTES;
    const unsigned char* bpg0 = Bp + ((size_t)g * B_TILES_N + 2 * ntc)     * NKT * TILE_BYTES;
    const unsigned char* bpg1 = Bp + ((size_t)g * B_TILES_N + 2 * ntc + 1) * NKT * TILE_BYTES;

    const int ldsch = wid * 1024;          // wave-uniform chunk base
    const int gch   = ldsch + lane * 16;   // per-lane global offset

    // fragment LDS offsets (within one 24 KB buffer; A at 0, B at 8192)
    const int fr = lane & 15;
    const int kh = lane >> 4;
    int afoff[4], bfoff[4];
    #pragma unroll
    for (int m = 0; m < 4; ++m)
        afoff[m] = swz(wr * 64 + m * 16 + fr, kh * 16);
    #pragma unroll
    for (int n = 0; n < 4; ++n) {
        const int row = wc * 64 + n * 16 + fr;
        bfoff[n] = ABYTES + (row >> 7) * 8192 + swz(row & 127, kh * 16);
    }

    v4i acc[4][4];
    #pragma unroll
    for (int i = 0; i < 4; ++i)
        #pragma unroll
        for (int j = 0; j < 4; ++j)
            acc[i][j] = (v4i){0, 0, 0, 0};

    // per-K-tile staging: A = 1 gload/thread, B = 2 gloads/thread
    auto stageA = [&](int kt) {
        unsigned char* la = &lds[(kt % 3) * BUFBYTES];
        gload16(apg + (size_t)kt * ABYTES + gch, la + ldsch);
    };
    auto stageB = [&](int kt) {
        unsigned char* la = &lds[(kt % 3) * BUFBYTES] + ABYTES;
        const size_t tk = (size_t)kt * 8192;
        gload16(bpg0 + tk + gch, la + ldsch);
        gload16(bpg1 + tk + gch, la + 8192 + ldsch);
    };

    // prologue: tiles 0,1 in flight (6 loads/thread); tile 0 resident
    stageA(0); stageB(0);
    stageA(1); stageB(1);
    asm volatile("s_waitcnt vmcnt(3)" ::: "memory");
    __syncthreads();

    #pragma unroll 1
    for (int kt = 0; kt < NKT; ++kt) {
        const unsigned char* lb = &lds[(kt % 3) * BUFBYTES];
        const bool pf = (kt + 2 < NKT);

        v4i af[2], af2[2], bf[4];

        // ---------- phase 0: m-frags 0-1 ----------
        // opening wait: tile kt resident (in-order vmcnt: the <=3
        // outstanding are tile kt+1's, issued after tile kt's)
        if (kt > 0) {
            if (kt < NKT - 1) asm volatile("s_waitcnt vmcnt(3)" ::: "memory");
            else              asm volatile("s_waitcnt vmcnt(0)" ::: "memory");
            BAR();
        }

        af[0] = *(const v4i*)(lb + afoff[0]);
        af[1] = *(const v4i*)(lb + afoff[1]);
        #pragma unroll
        for (int n = 0; n < 4; ++n) bf[n] = *(const v4i*)(lb + bfoff[n]);
        if (pf) stageA(kt + 2);

        __builtin_amdgcn_s_setprio(1);
        #pragma unroll
        for (int n = 0; n < 4; ++n)
            acc[0][n] = __builtin_amdgcn_mfma_i32_16x16x64_i8(af[0], bf[n], acc[0][n], 0, 0, 0);
        #pragma unroll
        for (int n = 0; n < 4; ++n)
            acc[1][n] = __builtin_amdgcn_mfma_i32_16x16x64_i8(af[1], bf[n], acc[1][n], 0, 0, 0);
        __builtin_amdgcn_s_setprio(0);

        // ---------- phase 1: m-frags 2-3 ----------
        BAR();

        af2[0] = *(const v4i*)(lb + afoff[2]);
        af2[1] = *(const v4i*)(lb + afoff[3]);
        if (pf) stageB(kt + 2);

        __builtin_amdgcn_s_setprio(1);
        #pragma unroll
        for (int n = 0; n < 4; ++n)
            acc[2][n] = __builtin_amdgcn_mfma_i32_16x16x64_i8(af2[0], bf[n], acc[2][n], 0, 0, 0);
        #pragma unroll
        for (int n = 0; n < 4; ++n)
            acc[3][n] = __builtin_amdgcn_mfma_i32_16x16x64_i8(af2[1], bf[n], acc[3][n], 0, 0, 0);
        __builtin_amdgcn_s_setprio(0);
    }

    // ---- epilogue: dequant + store ----
    #pragma unroll
    for (int mi = 0; mi < 4; ++mi) {
        const int r0 = brow + wr * 64 + mi * 16 + (lane >> 4) * 4;
        float pt[4];
        #pragma unroll
        for (int e = 0; e < 4; ++e) pt[e] = pts[r0 + e];
        #pragma unroll
        for (int ni = 0; ni < 4; ++ni) {
            const int col = bcol + wc * 64 + ni * 16 + (lane & 15);
            const float sc = scale[g * NN + col];
            #pragma unroll
            for (int e = 0; e < 4; ++e)
                out[(size_t)(r0 + e) * NN + col] = (float)acc[mi][ni][e] * sc * pt[e];
        }
    }
}

// ---- fused fallback (only if ws too small; round-1 verified kernel) ----
__global__ __launch_bounds__(256, 2)
void gg_i8(const int* __restrict__ A, const int* __restrict__ B,
           const float* __restrict__ scale, const float* __restrict__ pts,
           const int* __restrict__ glist, float* __restrict__ out)
{
    __shared__ unsigned char Ab[2][128 * 64];
    __shared__ unsigned char Bb[2][128 * 64];

    const int t    = threadIdx.x;
    const int lane = t & 63;
    const int wid  = t >> 6;
    const int wr   = wid >> 1;
    const int wc   = wid & 1;

    const int nwg  = gridDim.x;
    const int cpx  = nwg >> 3;
    const int bid  = blockIdx.x;
    const int swzb = (bid & 7) * cpx + (bid >> 3);
    const int mt   = swzb >> 5;
    const int nt   = swzb & 31;
    const int brow = mt * 128;
    const int bcol = nt * 128;

    int g = 0;
    #pragma unroll
    for (int i = 0; i < NG - 1; ++i)
        if (brow >= glist[i]) g = i + 1;
    const int* Bg = B + (size_t)g * (KK * NN);

    const int arow = t >> 4;
    const int acol = (t & 15) * 4;
    const int bkq = (t >> 5) * 8;
    const int bnq = (t & 31) * 4;

    const int* aP = A  + (size_t)(brow + arow) * KK + acol;
    const int* bP = Bg + (size_t)bkq * NN + bcol + bnq;

    int awoff[8];
    #pragma unroll
    for (int i = 0; i < 8; ++i) awoff[i] = swz(arow + i * 16, acol);
    int bwoff[4];
    #pragma unroll
    for (int ni = 0; ni < 4; ++ni) bwoff[ni] = swz(bnq + ni, bkq);

    const int fr = lane & 15;
    const int kh = lane >> 4;
    int afoff[4], bfoff[4];
    #pragma unroll
    for (int mi = 0; mi < 4; ++mi) afoff[mi] = swz(wr * 64 + mi * 16 + fr, kh * 16);
    #pragma unroll
    for (int ni = 0; ni < 4; ++ni) bfoff[ni] = swz(wc * 64 + ni * 16 + fr, kh * 16);

    v4i aL[8], bL[8];
    v4i acc[4][4];
    #pragma unroll
    for (int i = 0; i < 4; ++i)
        #pragma unroll
        for (int j = 0; j < 4; ++j)
            acc[i][j] = (v4i){0, 0, 0, 0};

    auto stage_load = [&](int kt) {
        const int* ap = aP + kt * 64;
        #pragma unroll
        for (int i = 0; i < 8; ++i)
            aL[i] = *(const v4i*)(ap + (size_t)i * 16 * KK);
        const int* bp = bP + (size_t)kt * 64 * NN;
        #pragma unroll
        for (int j = 0; j < 8; ++j)
            bL[j] = *(const v4i*)(bp + (size_t)j * NN);
    };

    auto stage_write = [&](int buf) {
        #pragma unroll
        for (int i = 0; i < 8; ++i)
            *(unsigned*)(&Ab[buf][awoff[i]]) = pack4(aL[i]);
        #pragma unroll
        for (int ni = 0; ni < 4; ++ni) {
            unsigned lo = (bL[0][ni] & 255) | ((bL[1][ni] & 255) << 8) |
                          ((bL[2][ni] & 255) << 16) | ((unsigned)bL[3][ni] << 24);
            unsigned hi = (bL[4][ni] & 255) | ((bL[5][ni] & 255) << 8) |
                          ((bL[6][ni] & 255) << 16) | ((unsigned)bL[7][ni] << 24);
            unsigned long long w = (unsigned long long)lo |
                                   ((unsigned long long)hi << 32);
            *(unsigned long long*)(&Bb[buf][bwoff[ni]]) = w;
        }
    };

    stage_load(0);
    stage_write(0);
    __syncthreads();

    int cur = 0;
    for (int kt = 0; kt < NKT; ++kt) {
        const bool pf = (kt + 1 < NKT);
        if (pf) stage_load(kt + 1);

        v4i af[4], bfr[4];
        #pragma unroll
        for (int mi = 0; mi < 4; ++mi)
            af[mi] = *(const v4i*)(&Ab[cur][afoff[mi]]);
        #pragma unroll
        for (int ni = 0; ni < 4; ++ni)
            bfr[ni] = *(const v4i*)(&Bb[cur][bfoff[ni]]);

        #pragma unroll
        for (int mi = 0; mi < 4; ++mi)
            #pragma unroll
            for (int ni = 0; ni < 4; ++ni)
                acc[mi][ni] = __builtin_amdgcn_mfma_i32_16x16x64_i8(
                    af[mi], bfr[ni], acc[mi][ni], 0, 0, 0);

        if (pf) stage_write(cur ^ 1);
        __syncthreads();
        cur ^= 1;
    }

    #pragma unroll
    for (int mi = 0; mi < 4; ++mi) {
        const int r0 = brow + wr * 64 + mi * 16 + (lane >> 4) * 4;
        #pragma unroll
        for (int ni = 0; ni < 4; ++ni) {
            const int col = bcol + wc * 64 + ni * 16 + (lane & 15);
            const float sc = scale[g * NN + col];
            #pragma unroll
            for (int e = 0; e < 4; ++e) {
                const int r = r0 + e;
                out[(size_t)r * NN + col] = (float)acc[mi][ni][e] * sc * pts[r];
            }
        }
    }
}

extern "C" void kernel_launch(void* const* d_in, const int* in_sizes, int n_in,
                              void* d_out, int out_size, void* d_ws, size_t ws_size,
                              hipStream_t stream) {
    const int*   A     = (const int*)d_in[0];
    const int*   B     = (const int*)d_in[1];
    const float* scale = (const float*)d_in[2];
    const float* pts   = (const float*)d_in[3];
    const int*   glist = (const int*)d_in[4];
    float*       out   = (float*)d_out;

    if (ws_size >= AP_BYTES + BP_BYTES) {
        unsigned char* Ap = (unsigned char*)d_ws;
        unsigned char* Bp = Ap + AP_BYTES;
        pack_a<<<dim3(A_TILES_M * NKT), 256, 0, stream>>>(A, Ap);
        pack_b<<<dim3(NG * B_TILES_N * NKT), 256, 0, stream>>>(B, Bp);
        gg_i8o<<<dim3((MM / BM) * (NN / BN)), 512, 0, stream>>>(
            Ap, Bp, scale, pts, glist, out);
    } else {
        gg_i8<<<dim3((MM / 128) * (NN / 128)), 256, 0, stream>>>(
            A, B, scale, pts, glist, out);
    }
}